// Round 1
// baseline (288.353 us; speedup 1.0000x reference)
//
#include <hip/hip_runtime.h>
#include <hip/hip_bf16.h>

#define EMBED 128
#define HID   64
#define NPB   8            // nodes per block (4 pairs)

__global__ __launch_bounds__(256)
void lane_node_embed_kernel(const float* __restrict__ pos,      // [N,10,2]
                            const int*   __restrict__ idx_int,  // [N]
                            const int*   __restrict__ idx_turn, // [N]
                            const int*   __restrict__ idx_tc,   // [N]
                            const float* __restrict__ W1,       // [2,64]
                            const float* __restrict__ b1,       // [64]
                            const float* __restrict__ gam,      // [64]
                            const float* __restrict__ bet,      // [64]
                            const float* __restrict__ W2,       // [64,128]
                            const float* __restrict__ b2,       // [128]
                            const float* __restrict__ Ei,       // [3,128]
                            const float* __restrict__ Et,       // [3,128]
                            const float* __restrict__ Etc,      // [2,128]
                            float* __restrict__ out,            // [N,128]
                            int n_nodes)
{
    __shared__ float hbuf[2][9][HID];   // h rows for the current node pair

    const int tid  = threadIdx.x;
    const int lane = tid & 63;
    const int w    = tid >> 6;    // wave id 0..3
    const int o    = tid & 127;   // output dim
    const int s    = tid >> 7;    // which node of the pair (phase 3)

    // Per-thread W2 column in registers (reused across all NPB nodes).
    float wreg[HID];
    #pragma unroll
    for (int k = 0; k < HID; ++k) wreg[k] = W2[k * EMBED + o];
    const float b2v = b2[o];

    // Per-lane first-layer params (k = lane).
    const float w1x = W1[lane];
    const float w1y = W1[HID + lane];
    const float b1v = b1[lane];
    const float gv  = gam[lane];
    const float bev = bet[lane];

    const long long blockStart = (long long)blockIdx.x * NPB;

    for (int pair = 0; pair < NPB / 2; ++pair) {
        // ---------- Phase 2: hidden rows (2 nodes x 9 points = 18 rows) ----------
        #pragma unroll
        for (int i = 0; i < 5; ++i) {
            int r = w + 4 * i;            // wave-uniform row id
            if (r < 18) {
                int nd = (r >= 9) ? 1 : 0;
                int p  = r - nd * 9;
                long long gn = blockStart + pair * 2 + nd;
                if (gn < n_nodes) {
                    const float* pb = pos + (gn * 10 + p) * 2;
                    float x0 = pb[0], y0 = pb[1], x1 = pb[2], y1 = pb[3];
                    float dx = x1 - x0, dy = y1 - y0;
                    float inv = rsqrtf(fmaf(dx, dx, fmaf(dy, dy, 0.0f)) + 1e-6f);
                    // reference: dv / sqrt(sum + 1e-6)
                    dx *= inv; dy *= inv;

                    float h = fmaf(dx, w1x, fmaf(dy, w1y, b1v));

                    // wave-wide LayerNorm over 64 lanes
                    float ssum = h;
                    #pragma unroll
                    for (int m = 1; m < 64; m <<= 1) ssum += __shfl_xor(ssum, m, 64);
                    float mu = ssum * (1.0f / 64.0f);
                    float d  = h - mu;
                    float v2 = d * d;
                    #pragma unroll
                    for (int m = 1; m < 64; m <<= 1) v2 += __shfl_xor(v2, m, 64);
                    float var = v2 * (1.0f / 64.0f);

                    float hn = fmaf(d * rsqrtf(var + 1e-5f), gv, bev);
                    hn = fmaxf(hn, 0.0f);     // ReLU
                    hbuf[nd][p][lane] = hn;
                }
            }
        }
        __syncthreads();

        // ---------- Phase 3: 64->128 matmul + disc + max over 9 ----------
        long long gn = blockStart + pair * 2 + s;
        if (gn < n_nodes) {
            float disc = Ei [(long long)idx_int [gn] * EMBED + o]
                       + Et [(long long)idx_turn[gn] * EMBED + o]
                       + Etc[(long long)idx_tc  [gn] * EMBED + o];

            float mx = -1e30f;
            #pragma unroll
            for (int p = 0; p < 9; ++p) {
                const float4* hp = (const float4*)hbuf[s][p];  // wave-uniform addr -> broadcast
                float acc = 0.0f;
                #pragma unroll
                for (int k4 = 0; k4 < 16; ++k4) {
                    float4 hv = hp[k4];
                    acc = fmaf(hv.x, wreg[4 * k4 + 0], acc);
                    acc = fmaf(hv.y, wreg[4 * k4 + 1], acc);
                    acc = fmaf(hv.z, wreg[4 * k4 + 2], acc);
                    acc = fmaf(hv.w, wreg[4 * k4 + 3], acc);
                }
                mx = fmaxf(mx, acc);
            }
            out[gn * EMBED + o] = mx + b2v + disc;
        }
        __syncthreads();
    }
}

extern "C" void kernel_launch(void* const* d_in, const int* in_sizes, int n_in,
                              void* d_out, int out_size, void* d_ws, size_t ws_size,
                              hipStream_t stream) {
    const float* pos  = (const float*)d_in[0];
    const int*   ii   = (const int*)  d_in[1];
    const int*   it   = (const int*)  d_in[2];
    const int*   itc  = (const int*)  d_in[3];
    const float* W1   = (const float*)d_in[4];
    const float* b1   = (const float*)d_in[5];
    const float* gam  = (const float*)d_in[6];
    const float* bet  = (const float*)d_in[7];
    const float* W2   = (const float*)d_in[8];
    const float* b2   = (const float*)d_in[9];
    const float* Ei   = (const float*)d_in[10];
    const float* Et   = (const float*)d_in[11];
    const float* Etc  = (const float*)d_in[12];
    float* out = (float*)d_out;

    int n_nodes = in_sizes[1];                    // B*L = 65536
    int blocks  = (n_nodes + NPB - 1) / NPB;

    hipLaunchKernelGGL(lane_node_embed_kernel, dim3(blocks), dim3(256), 0, stream,
                       pos, ii, it, itc, W1, b1, gam, bet, W2, b2, Ei, Et, Etc,
                       out, n_nodes);
}

// Round 2
// 66.234 us; speedup vs baseline: 4.3536x; 4.3536x over previous
//
#include <hip/hip_runtime.h>
#include <hip/hip_bf16.h>

#define NB      16          // nodes per block
#define THREADS 256

typedef float f32x4  __attribute__((ext_vector_type(4)));
typedef short bf16x8 __attribute__((ext_vector_type(8)));

static __device__ __forceinline__ unsigned short f2bf(float f) {
    __hip_bfloat16 h = __float2bfloat16(f);   // RNE
    return __builtin_bit_cast(unsigned short, h);
}

__global__ __launch_bounds__(THREADS)
void lane_node_embed_mfma(const float* __restrict__ pos,      // [N,10,2]
                          const int*   __restrict__ idx_int,  // [N]
                          const int*   __restrict__ idx_turn, // [N]
                          const int*   __restrict__ idx_tc,   // [N]
                          const float* __restrict__ W1,       // [2,64]
                          const float* __restrict__ b1,       // [64]
                          const float* __restrict__ gam,      // [64]
                          const float* __restrict__ bet,      // [64]
                          const float* __restrict__ W2,       // [64,128]
                          const float* __restrict__ b2,       // [128]
                          const float* __restrict__ Ei,       // [3,128]
                          const float* __restrict__ Et,       // [3,128]
                          const float* __restrict__ Etc,      // [2,128]
                          float* __restrict__ out,            // [N,128]
                          int n_nodes)
{
    // H: [NB nodes][16 rows][64 bf16] as 16B chunks, XOR-swizzled: chunk' = chunk ^ (row&7)
    __shared__ uint4 Hb[NB * 16 * 8];         // 32 KB

    const int tid  = threadIdx.x;
    const int lane = tid & 63;
    const int wv   = tid >> 6;
    const int blockStart = blockIdx.x * NB;

    // ---- zero the 7 pad rows of each node-tile (rows p=9..15) ----
    for (int i = tid; i < NB * 7 * 8; i += THREADS) {
        int rowp = i >> 3, ch = i & 7;
        int nd = rowp / 7, pr = rowp - nd * 7;
        Hb[(nd * 16 + 9 + pr) * 8 + ch] = make_uint4(0, 0, 0, 0);
    }

    // ---- Phase A: thread-per-row MLP1 + LayerNorm + ReLU -> bf16 H in LDS ----
    if (tid < NB * 9) {
        int nd = tid / 9, p = tid - nd * 9;
        int gn = blockStart + nd;
        if (gn < n_nodes) {
            const float2* pp = (const float2*)pos + (size_t)gn * 10 + p;
            float2 p0 = pp[0], p1 = pp[1];
            float dx = p1.x - p0.x, dy = p1.y - p0.y;
            float inv = rsqrtf(fmaf(dx, dx, fmaf(dy, dy, 1e-6f)));
            dx *= inv; dy *= inv;

            float h[64];
            float s = 0.f;
            #pragma unroll
            for (int k = 0; k < 64; ++k) {
                h[k] = fmaf(dx, W1[k], fmaf(dy, W1[64 + k], b1[k]));  // uniform -> s_load
                s += h[k];
            }
            float mu = s * (1.f / 64.f);
            float v = 0.f;
            #pragma unroll
            for (int k = 0; k < 64; ++k) { float d = h[k] - mu; v = fmaf(d, d, v); }
            float is = rsqrtf(v * (1.f / 64.f) + 1e-5f);

            unsigned int pk[32];
            #pragma unroll
            for (int k2 = 0; k2 < 32; ++k2) {
                float a = fmaf((h[2 * k2]     - mu) * is, gam[2 * k2],     bet[2 * k2]);
                float b = fmaf((h[2 * k2 + 1] - mu) * is, gam[2 * k2 + 1], bet[2 * k2 + 1]);
                a = fmaxf(a, 0.f); b = fmaxf(b, 0.f);
                pk[k2] = ((unsigned)f2bf(b) << 16) | (unsigned)f2bf(a);
            }
            int row = nd * 16 + p;
            #pragma unroll
            for (int c = 0; c < 8; ++c) {
                Hb[row * 8 + (c ^ (row & 7))] =
                    make_uint4(pk[4 * c], pk[4 * c + 1], pk[4 * c + 2], pk[4 * c + 3]);
            }
        }
    }

    // ---- Build B fragments (W2 columns, bf16) straight from global into regs ----
    // wave -> 4 coltiles x 8 nodes:  ct in [ctb, ctb+4), nodes in [nb0, nb0+8)
    const int ctb = (wv & 1) * 4;
    const int nb0 = (wv >> 1) * 8;

    bf16x8 Bfr[4][2];
    #pragma unroll
    for (int c = 0; c < 4; ++c) {
        #pragma unroll
        for (int kt = 0; kt < 2; ++kt) {
            int col = (ctb + c) * 16 + (lane & 15);
            int k0  = kt * 32 + (lane >> 4) * 8;
            unsigned int w[4];
            #pragma unroll
            for (int j = 0; j < 4; ++j) {
                float f0 = W2[(k0 + 2 * j) * 128 + col];
                float f1 = W2[(k0 + 2 * j + 1) * 128 + col];
                w[j] = ((unsigned)f2bf(f1) << 16) | (unsigned)f2bf(f0);
            }
            uint4 u = make_uint4(w[0], w[1], w[2], w[3]);
            Bfr[c][kt] = __builtin_bit_cast(bf16x8, u);
        }
    }

    // hoist b2 for this wave's 4 coltiles (use lane&15 so all lanes defined)
    float b2c[4];
    #pragma unroll
    for (int c = 0; c < 4; ++c) b2c[c] = b2[(ctb + c) * 16 + (lane & 15)];

    __syncthreads();

    // ---- Phase B: per node, A-frags from LDS, 8 MFMA, in-reg max reduce ----
    const int g = lane >> 4;
    for (int nn = 0; nn < 8; ++nn) {
        int nd = nb0 + nn;
        int gn = blockStart + nd;
        if (gn >= n_nodes) break;

        bf16x8 Afr[2];
        #pragma unroll
        for (int kt = 0; kt < 2; ++kt) {
            int row = nd * 16 + (lane & 15);
            int ch  = (kt * 4 + (lane >> 4)) ^ (lane & 7);
            Afr[kt] = __builtin_bit_cast(bf16x8, Hb[row * 8 + ch]);
        }

        f32x4 acc[4] = {{0.f,0.f,0.f,0.f},{0.f,0.f,0.f,0.f},
                        {0.f,0.f,0.f,0.f},{0.f,0.f,0.f,0.f}};
        #pragma unroll
        for (int c = 0; c < 4; ++c) {
            #pragma unroll
            for (int kt = 0; kt < 2; ++kt)
                acc[c] = __builtin_amdgcn_mfma_f32_16x16x32_bf16(Afr[kt], Bfr[c][kt], acc[c], 0, 0, 0);
        }

        int ii = idx_int[gn]  * 128;
        int tt = idx_turn[gn] * 128;
        int cc = idx_tc[gn]   * 128;

        #pragma unroll
        for (int c = 0; c < 4; ++c) {
            f32x4 a = acc[c];
            // lane's 4 regs = node-local rows 4g..4g+3; valid rows are 0..8
            float m = fmaxf(fmaxf(a[0], a[1]), fmaxf(a[2], a[3]));
            if (g == 2) m = a[0];            // only row 8 valid
            if (g == 3) m = -INFINITY;       // rows 12..15 all pad
            m = fmaxf(m, __shfl_xor(m, 16, 64));
            m = fmaxf(m, __shfl_xor(m, 32, 64));
            if (lane < 16) {
                int col = (ctb + c) * 16 + lane;
                out[(size_t)gn * 128 + col] =
                    m + b2c[c] + Ei[ii + col] + Et[tt + col] + Etc[cc + col];
            }
        }
    }
}

extern "C" void kernel_launch(void* const* d_in, const int* in_sizes, int n_in,
                              void* d_out, int out_size, void* d_ws, size_t ws_size,
                              hipStream_t stream) {
    const float* pos  = (const float*)d_in[0];
    const int*   ii   = (const int*)  d_in[1];
    const int*   it   = (const int*)  d_in[2];
    const int*   itc  = (const int*)  d_in[3];
    const float* W1   = (const float*)d_in[4];
    const float* b1   = (const float*)d_in[5];
    const float* gam  = (const float*)d_in[6];
    const float* bet  = (const float*)d_in[7];
    const float* W2   = (const float*)d_in[8];
    const float* b2   = (const float*)d_in[9];
    const float* Ei   = (const float*)d_in[10];
    const float* Et   = (const float*)d_in[11];
    const float* Etc  = (const float*)d_in[12];
    float* out = (float*)d_out;

    int n_nodes = in_sizes[1];                       // B*L = 65536
    int blocks  = (n_nodes + NB - 1) / NB;           // 4096

    hipLaunchKernelGGL(lane_node_embed_mfma, dim3(blocks), dim3(THREADS), 0, stream,
                       pos, ii, it, itc, W1, b1, gam, bet, W2, b2, Ei, Et, Etc,
                       out, n_nodes);
}

// Round 3
// 44.112 us; speedup vs baseline: 6.5369x; 1.5015x over previous
//
#include <hip/hip_runtime.h>
#include <hip/hip_bf16.h>

#define NB      16          // nodes per block
#define THREADS 256

// d_ws layout (float offsets)
#define WS_CST4   0         // 64 x float4 (u'=a*g, v'=b*g, w'=c*g, bet)
#define WS_QUAD   256       // 6 floats: E[a2],E[b2],E[ab],E[ac],E[bc],E[c2]+eps
#define WS_DISC   272       // 18*128 floats: b2 + Ei[a]+Et[b]+Etc[c]
#define WS_W2     2576      // 16 frags * 64 lanes * 16B (bf16 B-fragments)

typedef float f32x4  __attribute__((ext_vector_type(4)));
typedef short bf16x8 __attribute__((ext_vector_type(8)));

static __device__ __forceinline__ unsigned f2bf(float f) {
    __hip_bfloat16 h = __float2bfloat16(f);   // RNE
    return (unsigned)__builtin_bit_cast(unsigned short, h);
}

__global__ __launch_bounds__(THREADS)
void lane_setup_kernel(const float* __restrict__ W1, const float* __restrict__ b1,
                       const float* __restrict__ gam, const float* __restrict__ bet,
                       const float* __restrict__ W2, const float* __restrict__ b2,
                       const float* __restrict__ Ei, const float* __restrict__ Et,
                       const float* __restrict__ Etc, float* __restrict__ ws)
{
    const int tid = threadIdx.x, lane = tid & 63, wv = tid >> 6;

    // ---- wave 0: LN affine constants ----
    if (wv == 0) {
        float wx = W1[lane], wy = W1[64 + lane], bb = b1[lane];
        float sx = wx, sy = wy, sb = bb;
        #pragma unroll
        for (int m = 1; m < 64; m <<= 1) {
            sx += __shfl_xor(sx, m, 64);
            sy += __shfl_xor(sy, m, 64);
            sb += __shfl_xor(sb, m, 64);
        }
        float a = wx - sx * (1.f / 64.f);
        float b = wy - sy * (1.f / 64.f);
        float c = bb - sb * (1.f / 64.f);
        float p0 = a * a, p1 = b * b, p2 = a * b, p3 = a * c, p4 = b * c, p5 = c * c;
        #pragma unroll
        for (int m = 1; m < 64; m <<= 1) {
            p0 += __shfl_xor(p0, m, 64); p1 += __shfl_xor(p1, m, 64);
            p2 += __shfl_xor(p2, m, 64); p3 += __shfl_xor(p3, m, 64);
            p4 += __shfl_xor(p4, m, 64); p5 += __shfl_xor(p5, m, 64);
        }
        float g = gam[lane];
        ((float4*)(ws + WS_CST4))[lane] = make_float4(a * g, b * g, c * g, bet[lane]);
        if (lane == 0) {
            ws[WS_QUAD + 0] = p0 * (1.f / 64.f);
            ws[WS_QUAD + 1] = p1 * (1.f / 64.f);
            ws[WS_QUAD + 2] = p2 * (1.f / 64.f);
            ws[WS_QUAD + 3] = p3 * (1.f / 64.f);
            ws[WS_QUAD + 4] = p4 * (1.f / 64.f);
            ws[WS_QUAD + 5] = p5 * (1.f / 64.f) + 1e-5f;   // fold LN eps
        }
    }

    // ---- W2 bf16 fragments, exact per-lane MFMA-B layout ----
    {
        uint4* dst = (uint4*)(ws + WS_W2);
        #pragma unroll
        for (int f = wv * 4; f < wv * 4 + 4; ++f) {
            int c = f >> 1, kt = f & 1;
            int col = c * 16 + (lane & 15);
            int k0  = kt * 32 + (lane >> 4) * 8;
            unsigned w[4];
            #pragma unroll
            for (int j = 0; j < 4; ++j) {
                unsigned lo = f2bf(W2[(k0 + 2 * j) * 128 + col]);
                unsigned hi = f2bf(W2[(k0 + 2 * j + 1) * 128 + col]);
                w[j] = (hi << 16) | lo;
            }
            dst[f * 64 + lane] = make_uint4(w[0], w[1], w[2], w[3]);
        }
    }

    // ---- disc table: all 18 (a,b,c) combos, b2 folded in ----
    for (int i = tid; i < 18 * 128; i += THREADS) {
        int combo = i >> 7, col = i & 127;
        int ai = combo / 6; int r = combo - ai * 6; int bi = r >> 1; int ci = r & 1;
        ws[WS_DISC + i] = b2[col] + Ei[ai * 128 + col] + Et[bi * 128 + col] + Etc[ci * 128 + col];
    }
}

__global__ __launch_bounds__(THREADS)
void lane_node_embed_mfma(const float* __restrict__ pos,      // [N,10,2]
                          const int*   __restrict__ idx_int,  // [N]
                          const int*   __restrict__ idx_turn, // [N]
                          const int*   __restrict__ idx_tc,   // [N]
                          const float* __restrict__ ws,
                          float* __restrict__ out,            // [N,128]
                          int n_nodes)
{
    __shared__ uint4 Hb[NB * 16 * 8];   // 32 KB, chunk-swizzled: ch' = ch ^ (row&7)

    const int tid  = threadIdx.x;
    const int lane = tid & 63;
    const int wvu  = __builtin_amdgcn_readfirstlane(tid >> 6);
    const int blockStart = blockIdx.x * NB;

    // zero the pad rows (9..15) of each node tile
    for (int i = tid; i < NB * 7 * 8; i += THREADS) {
        int rowp = i >> 3, ch = i & 7;
        int nd = rowp / 7, pr = rowp - nd * 7;
        Hb[(nd * 16 + 9 + pr) * 8 + ch] = make_uint4(0, 0, 0, 0);
    }

    // ---- Phase A: closed-form MLP1+LN+ReLU, thread-per-row ----
    if (tid < NB * 9) {
        int nd = tid / 9, p = tid - nd * 9;
        int gn = blockStart + nd;
        if (gn < n_nodes) {
            const float2* pp = (const float2*)pos + (size_t)gn * 10 + p;
            float2 q0 = pp[0], q1 = pp[1];
            float dx = q1.x - q0.x, dy = q1.y - q0.y;
            float inv = rsqrtf(fmaf(dx, dx, fmaf(dy, dy, 1e-6f)));
            dx *= inv; dy *= inv;

            float qA = ws[WS_QUAD + 0], qB = ws[WS_QUAD + 1], qC = ws[WS_QUAD + 2];
            float qD = ws[WS_QUAD + 3], qE = ws[WS_QUAD + 4], qF = ws[WS_QUAD + 5];
            float t   = fmaf(dx * dy, qC, fmaf(dx, qD, dy * qE));
            float var = fmaf(2.f, t, fmaf(dx * dx, qA, fmaf(dy * dy, qB, qF)));
            float is  = rsqrtf(var);
            float ax = dx * is, ay = dy * is;

            const float4* cst = (const float4*)(ws + WS_CST4);
            unsigned pk[32];
            #pragma unroll
            for (int k2 = 0; k2 < 32; ++k2) {
                float4 c0 = cst[2 * k2], c1 = cst[2 * k2 + 1];
                float va = fmaf(ax, c0.x, fmaf(ay, c0.y, fmaf(is, c0.z, c0.w)));
                float vb = fmaf(ax, c1.x, fmaf(ay, c1.y, fmaf(is, c1.z, c1.w)));
                va = fmaxf(va, 0.f); vb = fmaxf(vb, 0.f);
                pk[k2] = (f2bf(vb) << 16) | f2bf(va);
            }
            int row = nd * 16 + p;
            #pragma unroll
            for (int c = 0; c < 8; ++c)
                Hb[row * 8 + (c ^ (row & 7))] =
                    make_uint4(pk[4 * c], pk[4 * c + 1], pk[4 * c + 2], pk[4 * c + 3]);
        }
    }

    // ---- B fragments: 8 coalesced 16B loads from prepacked ws ----
    const int ctb = (wvu & 1) * 4;
    const int nb0 = (wvu >> 1) * 8;
    const uint4* wfr = (const uint4*)(ws + WS_W2);
    bf16x8 Bfr[4][2];
    #pragma unroll
    for (int c = 0; c < 4; ++c)
        #pragma unroll
        for (int kt = 0; kt < 2; ++kt)
            Bfr[c][kt] = __builtin_bit_cast(bf16x8, wfr[((ctb + c) * 2 + kt) * 64 + lane]);

    __syncthreads();

    // ---- Phase B: MFMA + in-reg max reduce + fused epilogue ----
    const int g = lane >> 4;
    const bool is_g2 = (g == 2), is_g3 = (g == 3);
    for (int nn = 0; nn < 8; ++nn) {
        int nd = nb0 + nn;
        int gn = blockStart + nd;            // wave-uniform
        if (gn >= n_nodes) break;

        int combo = (idx_int[gn] * 3 + idx_turn[gn]) * 2 + idx_tc[gn];
        const float* dline = ws + WS_DISC + combo * 128 + ctb * 16;

        bf16x8 Afr[2];
        #pragma unroll
        for (int kt = 0; kt < 2; ++kt) {
            int row = nd * 16 + (lane & 15);
            int ch  = (kt * 4 + g) ^ (lane & 7);
            Afr[kt] = __builtin_bit_cast(bf16x8, Hb[row * 8 + ch]);
        }

        f32x4 acc[4] = {{0.f,0.f,0.f,0.f},{0.f,0.f,0.f,0.f},
                        {0.f,0.f,0.f,0.f},{0.f,0.f,0.f,0.f}};
        #pragma unroll
        for (int c = 0; c < 4; ++c)
            #pragma unroll
            for (int kt = 0; kt < 2; ++kt)
                acc[c] = __builtin_amdgcn_mfma_f32_16x16x32_bf16(Afr[kt], Bfr[c][kt], acc[c], 0, 0, 0);

        float mf[4];
        #pragma unroll
        for (int c = 0; c < 4; ++c) {
            f32x4 a = acc[c];
            float m = fmaxf(fmaxf(a[0], a[1]), fmaxf(a[2], a[3]));  // rows 4g..4g+3
            m = is_g2 ? a[0] : m;          // only row 8 valid
            m = is_g3 ? -INFINITY : m;     // rows 12..15 pad
            m = fmaxf(m, __shfl_xor(m, 16, 64));
            m = fmaxf(m, __shfl_xor(m, 32, 64));
            mf[c] = m;
        }
        // lane l -> coltile l>>4, col ctb*16 + l : one full-wave coalesced store
        float v01 = (lane & 16) ? mf[1] : mf[0];
        float v23 = (lane & 16) ? mf[3] : mf[2];
        float v   = (lane & 32) ? v23 : v01;
        out[(size_t)gn * 128 + ctb * 16 + lane] = v + dline[lane];
    }
}

extern "C" void kernel_launch(void* const* d_in, const int* in_sizes, int n_in,
                              void* d_out, int out_size, void* d_ws, size_t ws_size,
                              hipStream_t stream) {
    const float* pos  = (const float*)d_in[0];
    const int*   ii   = (const int*)  d_in[1];
    const int*   it   = (const int*)  d_in[2];
    const int*   itc  = (const int*)  d_in[3];
    const float* W1   = (const float*)d_in[4];
    const float* b1   = (const float*)d_in[5];
    const float* gam  = (const float*)d_in[6];
    const float* bet  = (const float*)d_in[7];
    const float* W2   = (const float*)d_in[8];
    const float* b2   = (const float*)d_in[9];
    const float* Ei   = (const float*)d_in[10];
    const float* Et   = (const float*)d_in[11];
    const float* Etc  = (const float*)d_in[12];
    float* out = (float*)d_out;
    float* ws  = (float*)d_ws;

    int n_nodes = in_sizes[1];                       // B*L = 65536
    int blocks  = (n_nodes + NB - 1) / NB;           // 4096

    hipLaunchKernelGGL(lane_setup_kernel, dim3(1), dim3(THREADS), 0, stream,
                       W1, b1, gam, bet, W2, b2, Ei, Et, Etc, ws);
    hipLaunchKernelGGL(lane_node_embed_mfma, dim3(blocks), dim3(THREADS), 0, stream,
                       pos, ii, it, itc, ws, out, n_nodes);
}

// Round 4
// 34.829 us; speedup vs baseline: 8.2790x; 1.2665x over previous
//
#include <hip/hip_runtime.h>
#include <hip/hip_bf16.h>

#define NB      16          // nodes per block (one MFMA M-tile)
#define THREADS 256

// d_ws layout (float offsets)
#define WS_CST4   0         // 64 x float4 (u'=a*g, v'=b*g, w'=c*g, bet)
#define WS_QUAD   256       // 6 floats: E[a2],E[b2],E[ab],E[ac],E[bc],E[c2]+eps
#define WS_DISC   272       // 18*128 floats: b2 + Ei[a]+Et[b]+Etc[c]
#define WS_W2     2576      // 16 frags * 64 lanes * 16B (bf16 B-fragments)

typedef float f32x4  __attribute__((ext_vector_type(4)));
typedef short bf16x8 __attribute__((ext_vector_type(8)));

static __device__ __forceinline__ unsigned f2bf(float f) {
    __hip_bfloat16 h = __float2bfloat16(f);   // RNE
    return (unsigned)__builtin_bit_cast(unsigned short, h);
}

__global__ __launch_bounds__(THREADS)
void lane_setup_kernel(const float* __restrict__ W1, const float* __restrict__ b1,
                       const float* __restrict__ gam, const float* __restrict__ bet,
                       const float* __restrict__ W2, const float* __restrict__ b2,
                       const float* __restrict__ Ei, const float* __restrict__ Et,
                       const float* __restrict__ Etc, float* __restrict__ ws)
{
    const int tid = threadIdx.x, lane = tid & 63, wv = tid >> 6;

    if (wv == 0) {
        float wx = W1[lane], wy = W1[64 + lane], bb = b1[lane];
        float sx = wx, sy = wy, sb = bb;
        #pragma unroll
        for (int m = 1; m < 64; m <<= 1) {
            sx += __shfl_xor(sx, m, 64);
            sy += __shfl_xor(sy, m, 64);
            sb += __shfl_xor(sb, m, 64);
        }
        float a = wx - sx * (1.f / 64.f);
        float b = wy - sy * (1.f / 64.f);
        float c = bb - sb * (1.f / 64.f);
        float p0 = a * a, p1 = b * b, p2 = a * b, p3 = a * c, p4 = b * c, p5 = c * c;
        #pragma unroll
        for (int m = 1; m < 64; m <<= 1) {
            p0 += __shfl_xor(p0, m, 64); p1 += __shfl_xor(p1, m, 64);
            p2 += __shfl_xor(p2, m, 64); p3 += __shfl_xor(p3, m, 64);
            p4 += __shfl_xor(p4, m, 64); p5 += __shfl_xor(p5, m, 64);
        }
        float g = gam[lane];
        ((float4*)(ws + WS_CST4))[lane] = make_float4(a * g, b * g, c * g, bet[lane]);
        if (lane == 0) {
            ws[WS_QUAD + 0] = p0 * (1.f / 64.f);
            ws[WS_QUAD + 1] = p1 * (1.f / 64.f);
            ws[WS_QUAD + 2] = p2 * (1.f / 64.f);
            ws[WS_QUAD + 3] = p3 * (1.f / 64.f);
            ws[WS_QUAD + 4] = p4 * (1.f / 64.f);
            ws[WS_QUAD + 5] = p5 * (1.f / 64.f) + 1e-5f;   // fold LN eps
        }
    }

    // W2 bf16 fragments, exact per-lane MFMA-B layout
    {
        uint4* dst = (uint4*)(ws + WS_W2);
        #pragma unroll
        for (int f = wv * 4; f < wv * 4 + 4; ++f) {
            int c = f >> 1, kt = f & 1;
            int col = c * 16 + (lane & 15);
            int k0  = kt * 32 + (lane >> 4) * 8;
            unsigned w[4];
            #pragma unroll
            for (int j = 0; j < 4; ++j) {
                unsigned lo = f2bf(W2[(k0 + 2 * j) * 128 + col]);
                unsigned hi = f2bf(W2[(k0 + 2 * j + 1) * 128 + col]);
                w[j] = (hi << 16) | lo;
            }
            dst[f * 64 + lane] = make_uint4(w[0], w[1], w[2], w[3]);
        }
    }

    // disc table: all 18 (a,b,c) combos, b2 folded in
    for (int i = tid; i < 18 * 128; i += THREADS) {
        int combo = i >> 7, col = i & 127;
        int ai = combo / 6; int r = combo - ai * 6; int bi = r >> 1; int ci = r & 1;
        ws[WS_DISC + i] = b2[col] + Ei[ai * 128 + col] + Et[bi * 128 + col] + Etc[ci * 128 + col];
    }
}

__global__ __launch_bounds__(THREADS)
void lane_node_embed_mfma(const float* __restrict__ pos,      // [N,10,2]
                          const int*   __restrict__ idx_int,  // [N]
                          const int*   __restrict__ idx_turn, // [N]
                          const int*   __restrict__ idx_tc,   // [N]
                          const float* __restrict__ ws,
                          float* __restrict__ out,            // [N,128]
                          int n_nodes)
{
    // H[node][p][64 bf16], 16B-chunk swizzle: chunk' = chunk ^ (node&7)
    __shared__ unsigned short H[NB * 9 * 64];   // 18 KB
    __shared__ float4 smv[NB * 9];              // per-row (ax, ay, is, 0)
    __shared__ int    cmb_lds[NB];

    const int tid  = threadIdx.x;
    const int lane = tid & 63;
    const int wv   = __builtin_amdgcn_readfirstlane(tid >> 6);
    const int blockStart = blockIdx.x * NB;

    // per-lane LN constants (hidden unit k = lane): one coalesced 16B load
    const float4 cst = ((const float4*)(ws + WS_CST4))[lane];

    // B fragments for this wave's 2 coltiles (prepacked, coalesced)
    const int ct0 = wv * 2;
    const uint4* wfr = (const uint4*)(ws + WS_W2);
    bf16x8 Bfr[2][2];
    #pragma unroll
    for (int c = 0; c < 2; ++c)
        #pragma unroll
        for (int kt = 0; kt < 2; ++kt)
            Bfr[c][kt] = __builtin_bit_cast(bf16x8, wfr[((ct0 + c) * 2 + kt) * 64 + lane]);

    // ---- stash: per-row (ax, ay, is) + per-node combo ----
    if (tid < NB * 9) {
        int nd = tid / 9, p = tid - nd * 9;
        int gn = blockStart + nd;
        float ax = 0.f, ay = 0.f, is = 0.f;
        if (gn < n_nodes) {
            const float2* pp = (const float2*)pos + (size_t)gn * 10 + p;
            float2 q0 = pp[0], q1 = pp[1];
            float dx = q1.x - q0.x, dy = q1.y - q0.y;
            float inv = rsqrtf(fmaf(dx, dx, fmaf(dy, dy, 1e-6f)));
            dx *= inv; dy *= inv;
            float qA = ws[WS_QUAD + 0], qB = ws[WS_QUAD + 1], qC = ws[WS_QUAD + 2];
            float qD = ws[WS_QUAD + 3], qE = ws[WS_QUAD + 4], qF = ws[WS_QUAD + 5];
            float t   = fmaf(dx * dy, qC, fmaf(dx, qD, dy * qE));
            float var = fmaf(2.f, t, fmaf(dx * dx, qA, fmaf(dy * dy, qB, qF)));
            is = rsqrtf(var);
            ax = dx * is; ay = dy * is;
        }
        smv[tid] = make_float4(ax, ay, is, 0.f);
    }
    if (tid < NB) {
        int gn = blockStart + tid;
        cmb_lds[tid] = (gn < n_nodes)
            ? (idx_int[gn] * 3 + idx_turn[gn]) * 2 + idx_tc[gn] : 0;
    }
    __syncthreads();

    // ---- Phase A: wave wv fills H rows for nodes 4wv..4wv+3 (lane = hidden k) ----
    {
        const int klo    = lane & 7;     // position within 16B chunk
        const int kchunk = lane >> 3;    // chunk 0..7
        #pragma unroll
        for (int i = 0; i < 4; ++i) {
            int node = wv * 4 + i;
            int s = node & 7;
            int widx = node * 576 + ((kchunk ^ s) << 3) + klo;
            #pragma unroll
            for (int p = 0; p < 9; ++p) {
                float4 t = smv[node * 9 + p];          // broadcast read
                float h = fmaf(t.x, cst.x, fmaf(t.y, cst.y, fmaf(t.z, cst.z, cst.w)));
                h = fmaxf(h, 0.f);                     // ReLU
                H[widx + p * 64] = (unsigned short)f2bf(h);
            }
        }
    }
    __syncthreads();

    // ---- Phase B: M-rows = 16 nodes; max over p via VALU between MFMAs ----
    const int g   = lane >> 4;
    const int l15 = lane & 15;
    const int sr  = l15 & 7;
    const int idx0 = l15 * 576 + (((0 + g) ^ sr) << 3);   // kt=0 chunk
    const int idx1 = l15 * 576 + (((4 + g) ^ sr) << 3);   // kt=1 chunk

    f32x4 mx0 = {-INFINITY, -INFINITY, -INFINITY, -INFINITY};
    f32x4 mx1 = mx0;
    const f32x4 zz = {0.f, 0.f, 0.f, 0.f};
    #pragma unroll
    for (int p = 0; p < 9; ++p) {
        bf16x8 a0 = *(const bf16x8*)&H[idx0 + p * 64];
        bf16x8 a1 = *(const bf16x8*)&H[idx1 + p * 64];
        f32x4 t0 = __builtin_amdgcn_mfma_f32_16x16x32_bf16(a0, Bfr[0][0], zz, 0, 0, 0);
        t0       = __builtin_amdgcn_mfma_f32_16x16x32_bf16(a1, Bfr[0][1], t0, 0, 0, 0);
        f32x4 t1 = __builtin_amdgcn_mfma_f32_16x16x32_bf16(a0, Bfr[1][0], zz, 0, 0, 0);
        t1       = __builtin_amdgcn_mfma_f32_16x16x32_bf16(a1, Bfr[1][1], t1, 0, 0, 0);
        #pragma unroll
        for (int k = 0; k < 4; ++k) {
            mx0[k] = fmaxf(mx0[k], t0[k]);
            mx1[k] = fmaxf(mx1[k], t1[k]);
        }
    }

    // ---- epilogue: lane holds (col = l15, nodes g*4+j); no cross-lane reduce ----
    #pragma unroll
    for (int c = 0; c < 2; ++c) {
        int col = (ct0 + c) * 16 + l15;
        f32x4 m = (c == 0) ? mx0 : mx1;
        #pragma unroll
        for (int j = 0; j < 4; ++j) {
            int nd = g * 4 + j;
            int gn = blockStart + nd;
            if (gn < n_nodes) {
                float dv = ws[WS_DISC + cmb_lds[nd] * 128 + col];
                out[(size_t)gn * 128 + col] = m[j] + dv;
            }
        }
    }
}

extern "C" void kernel_launch(void* const* d_in, const int* in_sizes, int n_in,
                              void* d_out, int out_size, void* d_ws, size_t ws_size,
                              hipStream_t stream) {
    const float* pos  = (const float*)d_in[0];
    const int*   ii   = (const int*)  d_in[1];
    const int*   it   = (const int*)  d_in[2];
    const int*   itc  = (const int*)  d_in[3];
    const float* W1   = (const float*)d_in[4];
    const float* b1   = (const float*)d_in[5];
    const float* gam  = (const float*)d_in[6];
    const float* bet  = (const float*)d_in[7];
    const float* W2   = (const float*)d_in[8];
    const float* b2   = (const float*)d_in[9];
    const float* Ei   = (const float*)d_in[10];
    const float* Et   = (const float*)d_in[11];
    const float* Etc  = (const float*)d_in[12];
    float* out = (float*)d_out;
    float* ws  = (float*)d_ws;

    int n_nodes = in_sizes[1];                       // B*L = 65536
    int blocks  = (n_nodes + NB - 1) / NB;           // 4096

    hipLaunchKernelGGL(lane_setup_kernel, dim3(1), dim3(THREADS), 0, stream,
                       W1, b1, gam, bet, W2, b2, Ei, Et, Etc, ws);
    hipLaunchKernelGGL(lane_node_embed_mfma, dim3(blocks), dim3(THREADS), 0, stream,
                       pos, ii, it, itc, ws, out, n_nodes);
}